// Round 1
// 345.322 us; speedup vs baseline: 1.0408x; 1.0408x over previous
//
#include <hip/hip_runtime.h>
#include <math.h>

typedef unsigned short u16;
typedef unsigned int   u32;
using f32x4  = __attribute__((ext_vector_type(4))) float;
using bf16x8 = __attribute__((ext_vector_type(8))) __bf16;

#define HIDDEN   2880
#define QKVD     5120
#define QD       4096
#define TTOK     2048
#define NKV      8
#define QMULT    8
#define HD       64
#define NPAD     2944   // w_out rows padded to 23*128 (unchanged; GEMM2 store-guards col<2944)

// prep grid partition
#define PREP_QKV_BLOCKS  14400   // QKVD*HIDDEN/4/256
#define PREP_WOUT_BLOCKS 11776   // NPAD*QD/4/256
#define PREP_RMS_BLOCKS  2048

static __device__ __forceinline__ float bflo(u32 u){ return __uint_as_float(u << 16); }
static __device__ __forceinline__ float bfhi(u32 u){ return __uint_as_float(u & 0xffff0000u); }
static __device__ __forceinline__ u16 f2bf(float f){
    u32 u = __float_as_uint(f);
    u32 r = (u + 0x7fffu + ((u >> 16) & 1u)) >> 16;
    return (u16)r;
}

static __device__ __forceinline__ void glds16(const void* g, void* l) {
    __builtin_amdgcn_global_load_lds(
        (__attribute__((address_space(1))) void*)g,
        (__attribute__((address_space(3))) void*)l,
        16, 0, 0);
}

// raw barrier: no implicit vmcnt(0) drain (keeps global_load_lds in flight across it);
// "memory" clobber = compiler fence so LDS loads / glds issues can't migrate across.
#define BAR() asm volatile("s_barrier" ::: "memory")

// ---------------- fused prep: w_qkv cvt | w_out cvt+pad | rmsnorm ----------------
__global__ __launch_bounds__(256) void prep_kernel(const float* __restrict__ w_qkv,
                                                   u16* __restrict__ wqkv_bf,
                                                   const float* __restrict__ w_out,
                                                   u16* __restrict__ wout_bf,
                                                   const float* __restrict__ x,
                                                   const float* __restrict__ scale,
                                                   u16* __restrict__ h) {
    const int b = blockIdx.x;
    const int tid = threadIdx.x;
    if (b < PREP_QKV_BLOCKS) {
        int i = b * 256 + tid;
        float4 f = ((const float4*)w_qkv)[i];
        ushort4 o;
        o.x = f2bf(f.x); o.y = f2bf(f.y); o.z = f2bf(f.z); o.w = f2bf(f.w);
        ((ushort4*)wqkv_bf)[i] = o;
    } else if (b < PREP_QKV_BLOCKS + PREP_WOUT_BLOCKS) {
        int i = (b - PREP_QKV_BLOCKS) * 256 + tid;
        int idx = i * 4;
        int row = idx >> 12;        // /4096
        int col = idx & 4095;
        ushort4 o;
        if (row < HIDDEN) {
            float4 f = *(const float4*)(w_out + (long)row * QD + col);
            o.x = f2bf(f.x); o.y = f2bf(f.y); o.z = f2bf(f.z); o.w = f2bf(f.w);
        } else {
            o.x = 0; o.y = 0; o.z = 0; o.w = 0;
        }
        ((ushort4*)wout_bf)[i] = o;
    } else {
        const int t = b - (PREP_QKV_BLOCKS + PREP_WOUT_BLOCKS);
        const float4* xr = (const float4*)(x + (long)t * HIDDEN);
        float4 v[3];
        float ss = 0.f;
        #pragma unroll
        for (int it = 0; it < 3; ++it) {
            int i4 = tid + it * 256;
            if (i4 < 720) {
                v[it] = xr[i4];
                ss += v[it].x*v[it].x + v[it].y*v[it].y + v[it].z*v[it].z + v[it].w*v[it].w;
            }
        }
        #pragma unroll
        for (int off = 32; off > 0; off >>= 1) ss += __shfl_down(ss, off);
        __shared__ float red[4];
        if ((tid & 63) == 0) red[tid >> 6] = ss;
        __syncthreads();
        float tot = red[0] + red[1] + red[2] + red[3];
        float rr = rsqrtf(tot * (1.0f / HIDDEN) + 1e-5f);
        ushort4* hr = (ushort4*)(h + (long)t * HIDDEN);
        #pragma unroll
        for (int it = 0; it < 3; ++it) {
            int i4 = tid + it * 256;
            if (i4 < 720) {
                float4 s4 = ((const float4*)scale)[i4];
                ushort4 o;
                o.x = f2bf(v[it].x * rr * s4.x);
                o.y = f2bf(v[it].y * rr * s4.y);
                o.z = f2bf(v[it].z * rr * s4.z);
                o.w = f2bf(v[it].w * rr * s4.w);
                hr[i4] = o;
            }
        }
    }
}

// ---------------- 8-phase 256x256/BK=64 GEMM: C = A[M,K] @ B[N,K]^T (bf16) -------
// m201-template port (T2 LDS XOR-swizzle + T3/T4 counted-vmcnt phases + T5 setprio),
// restructured as 4 phases per K-tile so any NT works (GEMM1 NT=45 odd).
// 512 thr = 8 waves (2M x 4N), wave tile 128x64, acc[8][4] f32x4 = 128 VGPR.
// LDS 128 KB dynamic: A[2][256][64] + B[2][256][64] bf16.
// Swizzle (rule #21, both-sides-or-neither): global_load_lds writes LINEARLY;
// the per-lane GLOBAL source 16B-granule is XOR'd with (row&7); ds_read applies
// the same XOR (folds into per-lane constants off0/off1). Kills the 16-way
// fragment-read bank conflict (even 8-lane/16B-slot spread).
// vmcnt discipline: one counted vmcnt(4) per K-tile (phase 4), never 0 mid-loop.
//   Drain proof: issue order per window t is [A(t+1)x4 | B(t+2)h0 x2 | B(t+2)h1 x2];
//   vmcnt(4) at the window's end leaves only B(t+2) outstanding => A(t+1),B(t+1)
//   complete before window t+1 reads them (barrier after vmcnt propagates across waves).

#define LOAD_AQ(MH) do { \
    aq[0][0] = *(const bf16x8*)(aS + (2*(MH)+0)*2048 + off0); \
    aq[0][1] = *(const bf16x8*)(aS + (2*(MH)+0)*2048 + off1); \
    aq[1][0] = *(const bf16x8*)(aS + (2*(MH)+1)*2048 + off0); \
    aq[1][1] = *(const bf16x8*)(aS + (2*(MH)+1)*2048 + off1); \
} while (0)

#define MFMA_Q(MH) do { \
    __builtin_amdgcn_s_setprio(1); \
    _Pragma("unroll") \
    for (int i2_ = 0; i2_ < 2; ++i2_) { \
        _Pragma("unroll") \
        for (int ni_ = 0; ni_ < 4; ++ni_) { \
            acc[2*(MH)+i2_][ni_] = __builtin_amdgcn_mfma_f32_16x16x32_bf16(aq[i2_][0], bq[ni_][0], acc[2*(MH)+i2_][ni_], 0, 0, 0); \
            acc[2*(MH)+i2_][ni_] = __builtin_amdgcn_mfma_f32_16x16x32_bf16(aq[i2_][1], bq[ni_][1], acc[2*(MH)+i2_][ni_], 0, 0, 0); \
        } \
    } \
    __builtin_amdgcn_s_setprio(0); \
} while (0)

__global__ __launch_bounds__(512, 2) void gemm_bt_8ph(const u16* __restrict__ A,
                                                      const u16* __restrict__ B,
                                                      u16* __restrict__ C0,
                                                      int N, int K, int ksplit,
                                                      int blimit, int colmax) {
    extern __shared__ u16 smem[];
    u16* const smA = smem;                 // [2][256][64] bf16 (32 KB/slot)
    u16* const smB = smem + 2 * 256 * 64;  // byte 65536
    const int tid  = threadIdx.x;
    const int lane = tid & 63;
    const int wv   = tid >> 6;             // wave 0..7
    const int wm   = wv >> 2;              // 0..1 (M)
    const int wn   = wv & 3;               // 0..3 (N)
    const long m0  = (long)blockIdx.y * 256;
    const long n0  = (long)blockIdx.x * 256;
    const int kbase = blockIdx.z * ksplit;
    const int NT   = ksplit >> 6;          // K-tiles of 64
    u16* C = C0 + (size_t)blockIdx.z * ((size_t)TTOK * N);

    // staging: per-thread 16B granule; source column pre-swizzled
    const int srow = tid >> 3;                              // 0..63
    const int sg8  = ((tid & 7) ^ (srow & 7)) << 3;         // src elem offset (swizzled)
    // fragment reads: swizzle folds to per-lane constants
    const int fr   = lane & 15;
    const int off0 = ((lane >> 4) << 4) ^ ((lane & 7) << 4);
    const int off1 = off0 ^ 64;
    const char* aR = (const char*)smA + (wm * 128 + fr) * 128;
    const char* bR = (const char*)smB + (wn * 64  + fr) * 128;

    f32x4 acc[8][4];
    #pragma unroll
    for (int i = 0; i < 8; ++i)
        #pragma unroll
        for (int j = 0; j < 4; ++j) acc[i][j] = f32x4{0.f, 0.f, 0.f, 0.f};

    const u16* Asrc = A + (m0 + srow) * (long)K + kbase + sg8;
    // stage both 128-row halves of A K-tile t -> slot t&1 (dest wave-uniform base;
    // HW distributes base + lane*16 = exactly our linear [row][64] layout)
    auto stageA = [&](int t) {
        char* dst = (char*)smA + (t & 1) * 32768 + (wv * 8) * 128;
        const u16* src = Asrc + t * 64;
        #pragma unroll
        for (int hj = 0; hj < 4; ++hj)
            glds16(src + (size_t)(hj * 64) * K, dst + hj * 64 * 128);
    };
    auto stageB = [&](int t, int h) {
        char* dst = (char*)smB + (t & 1) * 32768 + (h * 128 + wv * 8) * 128;
        #pragma unroll
        for (int j = 0; j < 2; ++j) {
            long r = n0 + h * 128 + j * 64 + srow;
            if (r > blimit) r = blimit;   // clamp into zero-padded rows (finite, unused cols guarded)
            glds16(B + (size_t)r * K + kbase + t * 64 + sg8, dst + j * 64 * 128);
        }
    };

    // prologue: A(0),B(0),B(1) staged; wait until A(0)+B(0) (first 8 loads) land
    stageA(0);
    stageB(0, 0); stageB(0, 1);
    if (NT > 1) { stageB(1, 0); stageB(1, 1); }
    if (NT < 3) asm volatile("s_waitcnt vmcnt(0)" ::: "memory");
    else        asm volatile("s_waitcnt vmcnt(4)" ::: "memory");
    BAR();

    for (int t = 0; t < NT; ++t) {
        const int sof = (t & 1) * 32768;
        const char* aS = aR + sof;
        const char* bS = bR + sof;
        bf16x8 bq[4][2], aq[2][2];
        // ---- phase 1: all B frags + A quadrant 0; prefetch A(t+1) (other slot)
        #pragma unroll
        for (int ni = 0; ni < 4; ++ni) {
            bq[ni][0] = *(const bf16x8*)(bS + ni * 2048 + off0);
            bq[ni][1] = *(const bf16x8*)(bS + ni * 2048 + off1);
        }
        LOAD_AQ(0);
        if (t + 1 < NT) stageA(t + 1);
        BAR();
        MFMA_Q(0);
        BAR();
        // ---- phase 2: A q1; prefetch B(t+2) half0 (this slot's B, consumed in ph1)
        LOAD_AQ(1);
        if (t + 2 < NT) stageB(t + 2, 0);
        BAR();
        MFMA_Q(1);
        BAR();
        // ---- phase 3: A q2; prefetch B(t+2) half1
        LOAD_AQ(2);
        if (t + 2 < NT) stageB(t + 2, 1);
        BAR();
        MFMA_Q(2);
        BAR();
        // ---- phase 4: A q3; K-tile checkpoint (counted, never 0 mid-loop)
        LOAD_AQ(3);
        BAR();
        MFMA_Q(3);
        if (t >= NT - 2) asm volatile("s_waitcnt vmcnt(0)" ::: "memory");
        else             asm volatile("s_waitcnt vmcnt(4)" ::: "memory");
        BAR();
    }

    // epilogue: C/D layout col=lane&15, row=(lane>>4)*4+reg  [m89-verified]
    const int cr = (lane >> 4) * 4;
    const int cc = lane & 15;
    #pragma unroll
    for (int ni = 0; ni < 4; ++ni) {
        long col = n0 + wn * 64 + ni * 16 + cc;
        if (col < colmax) {
            #pragma unroll
            for (int mi = 0; mi < 8; ++mi) {
                long row = m0 + wm * 128 + mi * 16 + cr;
                #pragma unroll
                for (int r2 = 0; r2 < 4; ++r2)
                    C[(row + r2) * (long)N + col] = f2bf(acc[mi][ni][r2]);
            }
        }
    }
}

// ---------------- RoPE (YaRN), consumes full-K GEMM1 output + bias ----------------
__global__ __launch_bounds__(256) void rope_kernel(const u16* __restrict__ p1,
                                                   const float* __restrict__ b_qkv,
                                                   u16* __restrict__ qr,
                                                   u16* __restrict__ kr,
                                                   u16* __restrict__ vr) {
    const int t = blockIdx.x;
    const int tid = threadIdx.x;
    __shared__ float cs[32], sn[32];
    if (tid < 32) {
        float fi = (float)tid;
        float freq   = exp2f(17.1946032f * (fi * (1.0f / 32.0f)));   // 150000^(i/32)
        float interp = 1.0f / (32.0f * freq);
        float extra  = 1.0f / freq;
        float ramp   = (fi - 8.0927802f) * (1.0f / (17.3980220f - 8.0927802f));
        float rc     = fminf(fmaxf(ramp, 0.0f), 1.0f);               // = 1 - mask
        float invf   = interp * rc + extra * (1.0f - rc);
        float ang    = (float)t * invf;
        cs[tid] = cosf(ang) * 1.3465736f;                            // * concentration
        sn[tid] = sinf(ang) * 1.3465736f;
    }
    __syncthreads();
    const u16* rowA = p1 + (long)t * QKVD;
    auto pair = [&](int col) -> float2 {
        u32 ua = *(const u32*)(rowA + col);
        float2 bb = *(const float2*)(b_qkv + col);
        return make_float2(bflo(ua) + bb.x, bfhi(ua) + bb.y);
    };
    // Q: 64 heads x 32 pairs
    for (int p = tid; p < 2048; p += 256) {
        int hd2 = p >> 5, i = p & 31;
        float2 ab = pair(hd2 * 64 + 2 * i);
        float o1 = ab.x * cs[i] - ab.y * sn[i];
        float o2 = ab.y * cs[i] + ab.x * sn[i];
        *(u32*)(qr + (long)t * QD + hd2 * 64 + 2 * i) = (u32)f2bf(o1) | ((u32)f2bf(o2) << 16);
    }
    // K: 8 heads x 32 pairs == 256 threads; head-major layout [kv][t][64]
    {
        int kv = tid >> 5, i = tid & 31;
        float2 ab = pair(QD + kv * 64 + 2 * i);
        float o1 = ab.x * cs[i] - ab.y * sn[i];
        float o2 = ab.y * cs[i] + ab.x * sn[i];
        *(u32*)(kr + ((long)kv * TTOK + t) * HD + 2 * i) = (u32)f2bf(o1) | ((u32)f2bf(o2) << 16);
    }
    // V: 8 heads x 64 = 256 u32; head-major [kv][t][64]
    {
        int kv = tid >> 5, d2 = tid & 31;
        float2 ab = pair(QD + 512 + kv * 64 + 2 * d2);
        *(u32*)(vr + ((long)kv * TTOK + t) * HD + 2 * d2) = (u32)f2bf(ab.x) | ((u32)f2bf(ab.y) << 16);
    }
}

// ---------------- MFMA sliding-window attention with sink ----------------
__global__ __launch_bounds__(256, 2) void attn_kernel(const u16* __restrict__ qr,
                                                      const u16* __restrict__ kr,
                                                      const u16* __restrict__ vr,
                                                      const float* __restrict__ sinks,
                                                      u16* __restrict__ o) {
    const int t0  = blockIdx.x * 16;
    const int h   = blockIdx.y;
    const int qhg = blockIdx.z;
    const int tid = threadIdx.x;
    const int lane = tid & 63, wv = tid >> 6;
    __shared__ __align__(16) u16 ks[144][72];    // K rows [key][64+pad]
    __shared__ __align__(16) u16 Vt[64][168];    // V^T [d][key], cols 144..159 zero
    __shared__ __align__(16) u16 P [4][16][168]; // per-wave P [token][key], cols 144..159 zero
    const u16* kb = kr + (long)h * TTOK * HD;
    const u16* vb = vr + (long)h * TTOK * HD;

    // stage K rows (coalesced)
    #pragma unroll
    for (int i = 0; i < 5; ++i) {
        int idx = i * 256 + tid;
        if (idx < 144 * 8) {
            int rr = idx >> 3, c = idx & 7;
            int tk = t0 - 128 + rr;
            int tks = tk < 0 ? 0 : tk;          // clamped; masked later
            *(uint4*)&ks[rr][c * 8] = *(const uint4*)(kb + (long)tks * HD + c * 8);
        }
    }
    // stage V transposed: thread -> one key, 8 dims per pass
    #pragma unroll
    for (int c4 = 0; c4 < 8; ++c4) {
        if (tid < 144) {
            int tk = t0 - 128 + tid;
            int tks = tk < 0 ? 0 : tk;
            uint4 v4 = *(const uint4*)(vb + (long)tks * HD + c4 * 8);
            int d0 = c4 * 8;
            Vt[d0+0][tid] = (u16)(v4.x & 0xffff); Vt[d0+1][tid] = (u16)(v4.x >> 16);
            Vt[d0+2][tid] = (u16)(v4.y & 0xffff); Vt[d0+3][tid] = (u16)(v4.y >> 16);
            Vt[d0+4][tid] = (u16)(v4.z & 0xffff); Vt[d0+5][tid] = (u16)(v4.z >> 16);
            Vt[d0+6][tid] = (u16)(v4.w & 0xffff); Vt[d0+7][tid] = (u16)(v4.w >> 16);
        }
    }
    if (tid < 128) {
        *(uint4*)&Vt[tid >> 1][144 + (tid & 1) * 8] = uint4{0, 0, 0, 0};
    }
    if (lane < 32) {
        *(uint4*)&P[wv][lane >> 1][144 + (lane & 1) * 8] = uint4{0, 0, 0, 0};
    }
    __syncthreads();

    const int qh   = qhg * 4 + wv;
    const int head = h * QMULT + qh;
    const int fr = lane & 15, fk = (lane >> 4) * 8;
    const int cr = (lane >> 4) * 4;

    const u16* qrow = qr + (long)(t0 + fr) * QD + head * HD;
    bf16x8 qf0 = *(const bf16x8*)(qrow + fk);
    bf16x8 qf1 = *(const bf16x8*)(qrow + 32 + fk);

    const int kmin = 128 - t0;          // kk >= kmin <=> key token >= 0
    float lsum[4] = {0.f, 0.f, 0.f, 0.f};

    for (int nt = 0; nt < 9; ++nt) {
        bf16x8 b0 = *(const bf16x8*)&ks[nt * 16 + fr][fk];
        bf16x8 b1 = *(const bf16x8*)&ks[nt * 16 + fr][32 + fk];
        f32x4 s = f32x4{0.f, 0.f, 0.f, 0.f};
        s = __builtin_amdgcn_mfma_f32_16x16x32_bf16(qf0, b0, s, 0, 0, 0);
        s = __builtin_amdgcn_mfma_f32_16x16x32_bf16(qf1, b1, s, 0, 0, 0);
        const int kk = nt * 16 + fr;    // C-layout col = lane&15
        #pragma unroll
        for (int r = 0; r < 4; ++r) {
            int row = cr + r;           // token index within tile
            bool valid = (kk >= row) && (kk <= row + 128) && (kk >= kmin);
            float p = valid ? __expf(s[r] * 0.125f) : 0.0f;
            lsum[r] += p;
            P[wv][row][kk] = f2bf(p);
        }
    }

    f32x4 oacc[4];
    #pragma unroll
    for (int dt = 0; dt < 4; ++dt) oacc[dt] = f32x4{0.f, 0.f, 0.f, 0.f};
    #pragma unroll
    for (int k5 = 0; k5 < 5; ++k5) {
        const int k0 = k5 * 32;
        bf16x8 pa = *(const bf16x8*)&P[wv][fr][k0 + fk];
        #pragma unroll
        for (int dt = 0; dt < 4; ++dt) {
            bf16x8 vf = *(const bf16x8*)&Vt[dt * 16 + fr][k0 + fk];
            oacc[dt] = __builtin_amdgcn_mfma_f32_16x16x32_bf16(pa, vf, oacc[dt], 0, 0, 0);
        }
    }

    #pragma unroll
    for (int r = 0; r < 4; ++r) {
        float v = lsum[r];
        v += __shfl_xor(v, 1);
        v += __shfl_xor(v, 2);
        v += __shfl_xor(v, 4);
        v += __shfl_xor(v, 8);
        lsum[r] = v;
    }
    const float sk = exp2f(sinks[head]);
    float inv[4];
    #pragma unroll
    for (int r = 0; r < 4; ++r) inv[r] = 1.0f / (lsum[r] + sk);

    #pragma unroll
    for (int dt = 0; dt < 4; ++dt) {
        #pragma unroll
        for (int r = 0; r < 4; ++r) {
            o[(long)(t0 + cr + r) * QD + head * HD + dt * 16 + fr] = f2bf(oacc[dt][r] * inv[r]);
        }
    }
}

// ---------------- reduce GEMM2 partials + bias + residual -> out ----------------
__global__ __launch_bounds__(256) void reduce2_kernel(const u16* __restrict__ p2a,
                                                      const u16* __restrict__ p2b,
                                                      const float* __restrict__ x,
                                                      const float* __restrict__ b_out,
                                                      float* __restrict__ out) {
    const int row = blockIdx.y;
    const int c4 = blockIdx.x * 256 + threadIdx.x;   // float4 index within row
    if (c4 >= 720) return;
    const int col = c4 * 4;
    ushort4 ua = *(const ushort4*)(p2a + (long)row * NPAD + col);
    ushort4 ub = *(const ushort4*)(p2b + (long)row * NPAD + col);
    float4 xv = *(const float4*)(x + (long)row * HIDDEN + col);
    float4 bv = *(const float4*)(b_out + col);
    float4 o;
    o.x = xv.x + bv.x + __uint_as_float((u32)ua.x << 16) + __uint_as_float((u32)ub.x << 16);
    o.y = xv.y + bv.y + __uint_as_float((u32)ua.y << 16) + __uint_as_float((u32)ub.y << 16);
    o.z = xv.z + bv.z + __uint_as_float((u32)ua.z << 16) + __uint_as_float((u32)ub.z << 16);
    o.w = xv.w + bv.w + __uint_as_float((u32)ua.w << 16) + __uint_as_float((u32)ub.w << 16);
    *(float4*)(out + (long)row * HIDDEN + col) = o;
}

// ---------------- launcher ----------------
extern "C" void kernel_launch(void* const* d_in, const int* in_sizes, int n_in,
                              void* d_out, int out_size, void* d_ws, size_t ws_size,
                              hipStream_t stream) {
    const float* x      = (const float*)d_in[0];
    const float* nscale = (const float*)d_in[1];
    const float* w_qkv  = (const float*)d_in[2];
    const float* b_qkv  = (const float*)d_in[3];
    const float* sinks  = (const float*)d_in[4];
    const float* w_out  = (const float*)d_in[5];
    const float* b_out  = (const float*)d_in[6];
    float* out = (float*)d_out;

    static int smem_set = 0;
    if (!smem_set) {
        hipFuncSetAttribute((const void*)gemm_bt_8ph,
                            hipFuncAttributeMaxDynamicSharedMemorySize, 131072);
        smem_set = 1;
    }

    char* ws = (char*)d_ws;
    size_t off = 0;
    auto alloc = [&](size_t bytes) { void* p = ws + off; off += (bytes + 255) & ~(size_t)255; return p; };
    u16* wqkv_bf = (u16*)alloc((size_t)QKVD * HIDDEN * 2);     // 29.5 MB
    u16* wout_bf = (u16*)alloc((size_t)NPAD * QD * 2);         // 24.1 MB
    u16* h       = (u16*)alloc((size_t)TTOK * HIDDEN * 2);     // 11.8 MB
    u16* p1      = (u16*)alloc((size_t)2 * TTOK * QKVD * 2);   // 42.0 MB (only 1st half used now)
    u16* qrot    = (u16*)alloc((size_t)TTOK * QD * 2);         // 16.8 MB
    u16* krot    = (u16*)alloc((size_t)NKV * TTOK * HD * 2);   // 2.1 MB
    u16* vrot    = (u16*)alloc((size_t)NKV * TTOK * HD * 2);   // 2.1 MB
    // aliases (dead-after analysis):
    u16* attn = wqkv_bf;               // wqkv_bf dead after gemm1; attn [2048][4096] = 16.8 MB
    u16* p2   = p1;                    // p1 dead after rope; p2 = 2 x [2048][2944] = 24.1 MB

    prep_kernel<<<PREP_QKV_BLOCKS + PREP_WOUT_BLOCKS + PREP_RMS_BLOCKS, 256, 0, stream>>>(
        w_qkv, wqkv_bf, w_out, wout_bf, x, nscale, h);
    // GEMM1: full-K (z=1), 20x8 = 160 blocks, NT=45
    gemm_bt_8ph<<<dim3(QKVD / 256, TTOK / 256, 1), 512, 131072, stream>>>(
        h, wqkv_bf, p1, QKVD, HIDDEN, HIDDEN, QKVD - 1, QKVD);
    rope_kernel<<<TTOK, 256, 0, stream>>>(p1, b_qkv, qrot, krot, vrot);
    attn_kernel<<<dim3(TTOK / 16, NKV, 2), 256, 0, stream>>>(qrot, krot, vrot, sinks, attn);
    // GEMM2: split-K z=2, 12x8x2 = 192 blocks, NT=32; B rows clamped into zero pad,
    // stores guarded to col<NPAD
    gemm_bt_8ph<<<dim3((NPAD + 255) / 256, TTOK / 256, 2), 512, 131072, stream>>>(
        attn, wout_bf, p2, NPAD, QD, QD / 2, NPAD - 1, NPAD);
    reduce2_kernel<<<dim3(3, TTOK), 256, 0, stream>>>(
        p2, p2 + (size_t)TTOK * NPAD, x, b_out, out);
}

// Round 2
// 334.270 us; speedup vs baseline: 1.0752x; 1.0331x over previous
//
#include <hip/hip_runtime.h>
#include <math.h>

typedef unsigned short u16;
typedef unsigned int   u32;
using f32x4  = __attribute__((ext_vector_type(4))) float;
using bf16x8 = __attribute__((ext_vector_type(8))) __bf16;

#define HIDDEN   2880
#define QKVD     5120
#define QD       4096
#define TTOK     2048
#define NKV      8
#define QMULT    8
#define HD       64
#define NPAD     2944   // w_out rows padded to 23*128 (GEMM2 store-guards col<2944)

// prep grid partition (w_out cvt moved into the GEMM1 dispatch's idle CUs)
#define PREP_QKV_BLOCKS  14400   // QKVD*HIDDEN/4/256
#define PREP_RMS_BLOCKS  2048

static __device__ __forceinline__ float bflo(u32 u){ return __uint_as_float(u << 16); }
static __device__ __forceinline__ float bfhi(u32 u){ return __uint_as_float(u & 0xffff0000u); }
static __device__ __forceinline__ u16 f2bf(float f){
    u32 u = __float_as_uint(f);
    u32 r = (u + 0x7fffu + ((u >> 16) & 1u)) >> 16;
    return (u16)r;
}

static __device__ __forceinline__ void glds16(const void* g, void* l) {
    __builtin_amdgcn_global_load_lds(
        (__attribute__((address_space(1))) void*)g,
        (__attribute__((address_space(3))) void*)l,
        16, 0, 0);
}

// raw barrier: no implicit vmcnt(0) drain (keeps global_load_lds in flight across it)
#define BAR() asm volatile("s_barrier" ::: "memory")

// ---------------- fused prep: w_qkv cvt | rmsnorm ----------------
__global__ __launch_bounds__(256) void prep_kernel(const float* __restrict__ w_qkv,
                                                   u16* __restrict__ wqkv_bf,
                                                   const float* __restrict__ x,
                                                   const float* __restrict__ scale,
                                                   u16* __restrict__ h) {
    const int b = blockIdx.x;
    const int tid = threadIdx.x;
    if (b < PREP_QKV_BLOCKS) {
        int i = b * 256 + tid;
        float4 f = ((const float4*)w_qkv)[i];
        ushort4 o;
        o.x = f2bf(f.x); o.y = f2bf(f.y); o.z = f2bf(f.z); o.w = f2bf(f.w);
        ((ushort4*)wqkv_bf)[i] = o;
    } else {
        const int t = b - PREP_QKV_BLOCKS;
        const float4* xr = (const float4*)(x + (long)t * HIDDEN);
        float4 v[3];
        float ss = 0.f;
        #pragma unroll
        for (int it = 0; it < 3; ++it) {
            int i4 = tid + it * 256;
            if (i4 < 720) {
                v[it] = xr[i4];
                ss += v[it].x*v[it].x + v[it].y*v[it].y + v[it].z*v[it].z + v[it].w*v[it].w;
            }
        }
        #pragma unroll
        for (int off = 32; off > 0; off >>= 1) ss += __shfl_down(ss, off);
        __shared__ float red[4];
        if ((tid & 63) == 0) red[tid >> 6] = ss;
        __syncthreads();
        float tot = red[0] + red[1] + red[2] + red[3];
        float rr = rsqrtf(tot * (1.0f / HIDDEN) + 1e-5f);
        ushort4* hr = (ushort4*)(h + (long)t * HIDDEN);
        #pragma unroll
        for (int it = 0; it < 3; ++it) {
            int i4 = tid + it * 256;
            if (i4 < 720) {
                float4 s4 = ((const float4*)scale)[i4];
                ushort4 o;
                o.x = f2bf(v[it].x * rr * s4.x);
                o.y = f2bf(v[it].y * rr * s4.y);
                o.z = f2bf(v[it].z * rr * s4.z);
                o.w = f2bf(v[it].w * rr * s4.w);
                hr[i4] = o;
            }
        }
    }
}

// ---------------- 8-phase 256x256/BK=64 GEMM: C = A[M,K] @ B[N,K]^T (bf16) -------
// m201-template port; 4 phases per K-tile (works for odd NT).
// 512 thr = 8 waves (2M x 4N), wave tile 128x64, acc[8][4] f32x4.
// LDS 160 KB: A triple-buffered [3][256][64] (96 KB) + B double [2][256][64] (64 KB).
//   3 A-slots let stageA run at distance t+2 (same as B) -> ~2 K-tiles (~4000 cy)
//   of latency cover vs ~900 cy HBM; round-1's 2-slot A waited on a t+1 load
//   issued only ~500 cy earlier (the vmcnt(4) stall, ~8-11% of tile time).
// Swizzle (rule #21): global_load_lds writes LINEARLY; the per-lane GLOBAL source
// 16B-granule is XOR'd with (row&7); ds_read applies the same XOR (folds into
// per-lane constants off0/off1). Bank conflicts measured 0 in round 1.
// vmcnt: one counted vmcnt(8) per K-tile, never 0 mid-loop.
//   Drain proof: loads issued during tile t = A(t+2)x4 + B(t+2)x4 = 8; waiting
//   vmcnt(8) at end of t forces all of A(t+1),B(t+1) landed before tile t+1.
// Extra z-blocks (blockIdx.z >= nz_gemm) do the w_out f32->bf16+pad conversion:
// GEMM1's 160-block grid leaves 96 CUs idle; these memory-only blocks fill them
// (dispatched after the gemm blocks; 15%-of-peak HBM leaves ample BW).

#define LOAD_AQ(MH) do { \
    aq[0][0] = *(const bf16x8*)(aS + (2*(MH)+0)*2048 + off0); \
    aq[0][1] = *(const bf16x8*)(aS + (2*(MH)+0)*2048 + off1); \
    aq[1][0] = *(const bf16x8*)(aS + (2*(MH)+1)*2048 + off0); \
    aq[1][1] = *(const bf16x8*)(aS + (2*(MH)+1)*2048 + off1); \
} while (0)

#define MFMA_Q(MH) do { \
    __builtin_amdgcn_s_setprio(1); \
    _Pragma("unroll") \
    for (int i2_ = 0; i2_ < 2; ++i2_) { \
        _Pragma("unroll") \
        for (int ni_ = 0; ni_ < 4; ++ni_) { \
            acc[2*(MH)+i2_][ni_] = __builtin_amdgcn_mfma_f32_16x16x32_bf16(aq[i2_][0], bq[ni_][0], acc[2*(MH)+i2_][ni_], 0, 0, 0); \
            acc[2*(MH)+i2_][ni_] = __builtin_amdgcn_mfma_f32_16x16x32_bf16(aq[i2_][1], bq[ni_][1], acc[2*(MH)+i2_][ni_], 0, 0, 0); \
        } \
    } \
    __builtin_amdgcn_s_setprio(0); \
} while (0)

__global__ __launch_bounds__(512, 2) void gemm_bt_8ph(const u16* __restrict__ A,
                                                      const u16* __restrict__ B,
                                                      u16* __restrict__ C0,
                                                      int N, int K, int ksplit,
                                                      int blimit, int colmax,
                                                      int nz_gemm,
                                                      const float* __restrict__ wout_src,
                                                      u16* __restrict__ wout_dst) {
    const int tid  = threadIdx.x;

    if ((int)blockIdx.z >= nz_gemm) {
        // ---- filler blocks: w_out cvt+pad [HIDDEN][QD] f32 -> [NPAD][QD] bf16 ----
        const long nb = (long)gridDim.x * gridDim.y;      // blocks in this z-slice
        long bidx = (long)blockIdx.y * gridDim.x + blockIdx.x;
        long i = bidx * 512 + tid;
        const long tot = (long)NPAD * QD / 4;
        const long stride = nb * 512;
        for (; i < tot; i += stride) {
            long idx = i * 4;
            int row = (int)(idx >> 12);                   // /4096
            int col = (int)(idx & 4095);
            ushort4 o;
            if (row < HIDDEN) {
                float4 f = *(const float4*)(wout_src + (long)row * QD + col);
                o.x = f2bf(f.x); o.y = f2bf(f.y); o.z = f2bf(f.z); o.w = f2bf(f.w);
            } else {
                o.x = 0; o.y = 0; o.z = 0; o.w = 0;
            }
            ((ushort4*)wout_dst)[i] = o;
        }
        return;
    }

    extern __shared__ u16 smem[];
    u16* const smA = smem;                  // [3][256][64] bf16 (32 KB/slot)
    u16* const smB = smem + 3 * 256 * 64;   // byte 98304, [2][256][64]
    const int lane = tid & 63;
    const int wv   = tid >> 6;              // wave 0..7
    const int wm   = wv >> 2;               // 0..1 (M)
    const int wn   = wv & 3;                // 0..3 (N)
    const long m0  = (long)blockIdx.y * 256;
    const long n0  = (long)blockIdx.x * 256;
    const int kbase = blockIdx.z * ksplit;
    const int NT   = ksplit >> 6;           // K-tiles of 64
    u16* C = C0 + (size_t)blockIdx.z * ((size_t)TTOK * N);

    // staging: per-thread 16B granule; source column pre-swizzled
    const int srow = tid >> 3;                              // 0..63
    const int sg8  = ((tid & 7) ^ (srow & 7)) << 3;         // src elem offset (swizzled)
    // fragment reads: swizzle folds to per-lane constants
    const int fr   = lane & 15;
    const int off0 = ((lane >> 4) << 4) ^ ((lane & 7) << 4);
    const int off1 = off0 ^ 64;
    const char* aR = (const char*)smA + (wm * 128 + fr) * 128;
    const char* bR = (const char*)smB + (wn * 64  + fr) * 128;

    f32x4 acc[8][4];
    #pragma unroll
    for (int i = 0; i < 8; ++i)
        #pragma unroll
        for (int j = 0; j < 4; ++j) acc[i][j] = f32x4{0.f, 0.f, 0.f, 0.f};

    const u16* Asrc = A + (m0 + srow) * (long)K + kbase + sg8;
    auto stageA = [&](int t, int slot) {
        char* dst = (char*)smA + slot * 32768 + (wv * 8) * 128;
        const u16* src = Asrc + t * 64;
        #pragma unroll
        for (int hj = 0; hj < 4; ++hj)
            glds16(src + (size_t)(hj * 64) * K, dst + hj * 64 * 128);
    };
    auto stageB = [&](int t, int h) {
        char* dst = (char*)smB + (t & 1) * 32768 + (h * 128 + wv * 8) * 128;
        #pragma unroll
        for (int j = 0; j < 2; ++j) {
            long r = n0 + h * 128 + j * 64 + srow;
            if (r > blimit) r = blimit;   // clamp into zero-padded rows (cols store-guarded)
            glds16(B + (size_t)r * K + kbase + t * 64 + sg8, dst + j * 64 * 128);
        }
    };

    // prologue: A(0)->slot0, B(0); A(1)->slot1, B(1). 16 loads; vmcnt(8) leaves
    // only the newest 8 (A1,B1) outstanding => A0,B0 landed.
    stageA(0, 0);
    stageB(0, 0); stageB(0, 1);
    if (NT > 1) { stageA(1, 1); stageB(1, 0); stageB(1, 1); }
    if (NT > 1) asm volatile("s_waitcnt vmcnt(8)" ::: "memory");
    else        asm volatile("s_waitcnt vmcnt(0)" ::: "memory");
    BAR();

    int sA = 0;                             // A slot of tile t (t % 3)
    for (int t = 0; t < NT; ++t) {
        const char* aS = aR + sA * 32768;
        const char* bS = bR + (t & 1) * 32768;
        int sA2 = sA + 2; if (sA2 >= 3) sA2 -= 3;   // slot for t+2
        bf16x8 bq[4][2], aq[2][2];
        // ---- phase 1: all B frags + A quadrant 0; prefetch A(t+2) (3rd slot:
        //      distinct from live slots t and t+1; slot t+2==t-1 reads finished
        //      at tile t-1's last barrier)
        #pragma unroll
        for (int ni = 0; ni < 4; ++ni) {
            bq[ni][0] = *(const bf16x8*)(bS + ni * 2048 + off0);
            bq[ni][1] = *(const bf16x8*)(bS + ni * 2048 + off1);
        }
        LOAD_AQ(0);
        if (t + 2 < NT) stageA(t + 2, sA2);
        BAR();
        MFMA_Q(0);
        BAR();
        // ---- phase 2: A q1; prefetch B(t+2) half0 (slot t&1: bq reads completed
        //      by all waves before the post-MFMA0 barrier)
        LOAD_AQ(1);
        if (t + 2 < NT) stageB(t + 2, 0);
        BAR();
        MFMA_Q(1);
        BAR();
        // ---- phase 3: A q2; prefetch B(t+2) half1
        LOAD_AQ(2);
        if (t + 2 < NT) stageB(t + 2, 1);
        BAR();
        MFMA_Q(2);
        BAR();
        // ---- phase 4: A q3; K-tile checkpoint (counted, never 0 mid-loop)
        LOAD_AQ(3);
        BAR();
        MFMA_Q(3);
        if (t + 2 < NT)      asm volatile("s_waitcnt vmcnt(8)" ::: "memory");
        else if (t + 1 < NT) asm volatile("s_waitcnt vmcnt(0)" ::: "memory");
        BAR();
        sA = (sA == 2) ? 0 : sA + 1;
    }

    // epilogue: C/D layout col=lane&15, row=(lane>>4)*4+reg  [m89-verified]
    const int cr = (lane >> 4) * 4;
    const int cc = lane & 15;
    #pragma unroll
    for (int ni = 0; ni < 4; ++ni) {
        long col = n0 + wn * 64 + ni * 16 + cc;
        if (col < colmax) {
            #pragma unroll
            for (int mi = 0; mi < 8; ++mi) {
                long row = m0 + wm * 128 + mi * 16 + cr;
                #pragma unroll
                for (int r2 = 0; r2 < 4; ++r2)
                    C[(row + r2) * (long)N + col] = f2bf(acc[mi][ni][r2]);
            }
        }
    }
}

// ---------------- RoPE (YaRN), consumes full-K GEMM1 output + bias ----------------
__global__ __launch_bounds__(256) void rope_kernel(const u16* __restrict__ p1,
                                                   const float* __restrict__ b_qkv,
                                                   u16* __restrict__ qr,
                                                   u16* __restrict__ kr,
                                                   u16* __restrict__ vr) {
    const int t = blockIdx.x;
    const int tid = threadIdx.x;
    __shared__ float cs[32], sn[32];
    if (tid < 32) {
        float fi = (float)tid;
        float freq   = exp2f(17.1946032f * (fi * (1.0f / 32.0f)));   // 150000^(i/32)
        float interp = 1.0f / (32.0f * freq);
        float extra  = 1.0f / freq;
        float ramp   = (fi - 8.0927802f) * (1.0f / (17.3980220f - 8.0927802f));
        float rc     = fminf(fmaxf(ramp, 0.0f), 1.0f);               // = 1 - mask
        float invf   = interp * rc + extra * (1.0f - rc);
        float ang    = (float)t * invf;
        cs[tid] = cosf(ang) * 1.3465736f;                            // * concentration
        sn[tid] = sinf(ang) * 1.3465736f;
    }
    __syncthreads();
    const u16* rowA = p1 + (long)t * QKVD;
    auto pair = [&](int col) -> float2 {
        u32 ua = *(const u32*)(rowA + col);
        float2 bb = *(const float2*)(b_qkv + col);
        return make_float2(bflo(ua) + bb.x, bfhi(ua) + bb.y);
    };
    // Q: 64 heads x 32 pairs
    for (int p = tid; p < 2048; p += 256) {
        int hd2 = p >> 5, i = p & 31;
        float2 ab = pair(hd2 * 64 + 2 * i);
        float o1 = ab.x * cs[i] - ab.y * sn[i];
        float o2 = ab.y * cs[i] + ab.x * sn[i];
        *(u32*)(qr + (long)t * QD + hd2 * 64 + 2 * i) = (u32)f2bf(o1) | ((u32)f2bf(o2) << 16);
    }
    // K: 8 heads x 32 pairs == 256 threads; head-major layout [kv][t][64]
    {
        int kv = tid >> 5, i = tid & 31;
        float2 ab = pair(QD + kv * 64 + 2 * i);
        float o1 = ab.x * cs[i] - ab.y * sn[i];
        float o2 = ab.y * cs[i] + ab.x * sn[i];
        *(u32*)(kr + ((long)kv * TTOK + t) * HD + 2 * i) = (u32)f2bf(o1) | ((u32)f2bf(o2) << 16);
    }
    // V: 8 heads x 64 = 256 u32; head-major [kv][t][64]
    {
        int kv = tid >> 5, d2 = tid & 31;
        float2 ab = pair(QD + 512 + kv * 64 + 2 * d2);
        *(u32*)(vr + ((long)kv * TTOK + t) * HD + 2 * d2) = (u32)f2bf(ab.x) | ((u32)f2bf(ab.y) << 16);
    }
}

// ---------------- MFMA sliding-window attention with sink ----------------
__global__ __launch_bounds__(256, 2) void attn_kernel(const u16* __restrict__ qr,
                                                      const u16* __restrict__ kr,
                                                      const u16* __restrict__ vr,
                                                      const float* __restrict__ sinks,
                                                      u16* __restrict__ o) {
    const int t0  = blockIdx.x * 16;
    const int h   = blockIdx.y;
    const int qhg = blockIdx.z;
    const int tid = threadIdx.x;
    const int lane = tid & 63, wv = tid >> 6;
    __shared__ __align__(16) u16 ks[144][72];    // K rows [key][64+pad]
    __shared__ __align__(16) u16 Vt[64][168];    // V^T [d][key], cols 144..159 zero
    __shared__ __align__(16) u16 P [4][16][168]; // per-wave P [token][key], cols 144..159 zero
    const u16* kb = kr + (long)h * TTOK * HD;
    const u16* vb = vr + (long)h * TTOK * HD;

    // stage K rows (coalesced)
    #pragma unroll
    for (int i = 0; i < 5; ++i) {
        int idx = i * 256 + tid;
        if (idx < 144 * 8) {
            int rr = idx >> 3, c = idx & 7;
            int tk = t0 - 128 + rr;
            int tks = tk < 0 ? 0 : tk;          // clamped; masked later
            *(uint4*)&ks[rr][c * 8] = *(const uint4*)(kb + (long)tks * HD + c * 8);
        }
    }
    // stage V transposed: thread -> one key, 8 dims per pass
    #pragma unroll
    for (int c4 = 0; c4 < 8; ++c4) {
        if (tid < 144) {
            int tk = t0 - 128 + tid;
            int tks = tk < 0 ? 0 : tk;
            uint4 v4 = *(const uint4*)(vb + (long)tks * HD + c4 * 8);
            int d0 = c4 * 8;
            Vt[d0+0][tid] = (u16)(v4.x & 0xffff); Vt[d0+1][tid] = (u16)(v4.x >> 16);
            Vt[d0+2][tid] = (u16)(v4.y & 0xffff); Vt[d0+3][tid] = (u16)(v4.y >> 16);
            Vt[d0+4][tid] = (u16)(v4.z & 0xffff); Vt[d0+5][tid] = (u16)(v4.z >> 16);
            Vt[d0+6][tid] = (u16)(v4.w & 0xffff); Vt[d0+7][tid] = (u16)(v4.w >> 16);
        }
    }
    if (tid < 128) {
        *(uint4*)&Vt[tid >> 1][144 + (tid & 1) * 8] = uint4{0, 0, 0, 0};
    }
    if (lane < 32) {
        *(uint4*)&P[wv][lane >> 1][144 + (lane & 1) * 8] = uint4{0, 0, 0, 0};
    }
    __syncthreads();

    const int qh   = qhg * 4 + wv;
    const int head = h * QMULT + qh;
    const int fr = lane & 15, fk = (lane >> 4) * 8;
    const int cr = (lane >> 4) * 4;

    const u16* qrow = qr + (long)(t0 + fr) * QD + head * HD;
    bf16x8 qf0 = *(const bf16x8*)(qrow + fk);
    bf16x8 qf1 = *(const bf16x8*)(qrow + 32 + fk);

    const int kmin = 128 - t0;          // kk >= kmin <=> key token >= 0
    float lsum[4] = {0.f, 0.f, 0.f, 0.f};

    for (int nt = 0; nt < 9; ++nt) {
        bf16x8 b0 = *(const bf16x8*)&ks[nt * 16 + fr][fk];
        bf16x8 b1 = *(const bf16x8*)&ks[nt * 16 + fr][32 + fk];
        f32x4 s = f32x4{0.f, 0.f, 0.f, 0.f};
        s = __builtin_amdgcn_mfma_f32_16x16x32_bf16(qf0, b0, s, 0, 0, 0);
        s = __builtin_amdgcn_mfma_f32_16x16x32_bf16(qf1, b1, s, 0, 0, 0);
        const int kk = nt * 16 + fr;    // C-layout col = lane&15
        #pragma unroll
        for (int r = 0; r < 4; ++r) {
            int row = cr + r;           // token index within tile
            bool valid = (kk >= row) && (kk <= row + 128) && (kk >= kmin);
            float p = valid ? __expf(s[r] * 0.125f) : 0.0f;
            lsum[r] += p;
            P[wv][row][kk] = f2bf(p);
        }
    }

    f32x4 oacc[4];
    #pragma unroll
    for (int dt = 0; dt < 4; ++dt) oacc[dt] = f32x4{0.f, 0.f, 0.f, 0.f};
    #pragma unroll
    for (int k5 = 0; k5 < 5; ++k5) {
        const int k0 = k5 * 32;
        bf16x8 pa = *(const bf16x8*)&P[wv][fr][k0 + fk];
        #pragma unroll
        for (int dt = 0; dt < 4; ++dt) {
            bf16x8 vf = *(const bf16x8*)&Vt[dt * 16 + fr][k0 + fk];
            oacc[dt] = __builtin_amdgcn_mfma_f32_16x16x32_bf16(pa, vf, oacc[dt], 0, 0, 0);
        }
    }

    #pragma unroll
    for (int r = 0; r < 4; ++r) {
        float v = lsum[r];
        v += __shfl_xor(v, 1);
        v += __shfl_xor(v, 2);
        v += __shfl_xor(v, 4);
        v += __shfl_xor(v, 8);
        lsum[r] = v;
    }
    const float sk = exp2f(sinks[head]);
    float inv[4];
    #pragma unroll
    for (int r = 0; r < 4; ++r) inv[r] = 1.0f / (lsum[r] + sk);

    #pragma unroll
    for (int dt = 0; dt < 4; ++dt) {
        #pragma unroll
        for (int r = 0; r < 4; ++r) {
            o[(long)(t0 + cr + r) * QD + head * HD + dt * 16 + fr] = f2bf(oacc[dt][r] * inv[r]);
        }
    }
}

// ---------------- reduce GEMM2 partials + bias + residual -> out ----------------
__global__ __launch_bounds__(256) void reduce2_kernel(const u16* __restrict__ p2a,
                                                      const u16* __restrict__ p2b,
                                                      const float* __restrict__ x,
                                                      const float* __restrict__ b_out,
                                                      float* __restrict__ out) {
    const int row = blockIdx.y;
    const int c4 = blockIdx.x * 256 + threadIdx.x;   // float4 index within row
    if (c4 >= 720) return;
    const int col = c4 * 4;
    ushort4 ua = *(const ushort4*)(p2a + (long)row * NPAD + col);
    ushort4 ub = *(const ushort4*)(p2b + (long)row * NPAD + col);
    float4 xv = *(const float4*)(x + (long)row * HIDDEN + col);
    float4 bv = *(const float4*)(b_out + col);
    float4 o;
    o.x = xv.x + bv.x + __uint_as_float((u32)ua.x << 16) + __uint_as_float((u32)ub.x << 16);
    o.y = xv.y + bv.y + __uint_as_float((u32)ua.y << 16) + __uint_as_float((u32)ub.y << 16);
    o.z = xv.z + bv.z + __uint_as_float((u32)ua.z << 16) + __uint_as_float((u32)ub.z << 16);
    o.w = xv.w + bv.w + __uint_as_float((u32)ua.w << 16) + __uint_as_float((u32)ub.w << 16);
    *(float4*)(out + (long)row * HIDDEN + col) = o;
}

// ---------------- launcher ----------------
extern "C" void kernel_launch(void* const* d_in, const int* in_sizes, int n_in,
                              void* d_out, int out_size, void* d_ws, size_t ws_size,
                              hipStream_t stream) {
    const float* x      = (const float*)d_in[0];
    const float* nscale = (const float*)d_in[1];
    const float* w_qkv  = (const float*)d_in[2];
    const float* b_qkv  = (const float*)d_in[3];
    const float* sinks  = (const float*)d_in[4];
    const float* w_out  = (const float*)d_in[5];
    const float* b_out  = (const float*)d_in[6];
    float* out = (float*)d_out;

    static int smem_set = 0;
    if (!smem_set) {
        hipFuncSetAttribute((const void*)gemm_bt_8ph,
                            hipFuncAttributeMaxDynamicSharedMemorySize, 163840);
        smem_set = 1;
    }

    char* ws = (char*)d_ws;
    size_t off = 0;
    auto alloc = [&](size_t bytes) { void* p = ws + off; off += (bytes + 255) & ~(size_t)255; return p; };
    u16* wqkv_bf = (u16*)alloc((size_t)QKVD * HIDDEN * 2);     // 29.5 MB
    u16* wout_bf = (u16*)alloc((size_t)NPAD * QD * 2);         // 24.1 MB
    u16* h       = (u16*)alloc((size_t)TTOK * HIDDEN * 2);     // 11.8 MB
    u16* p1      = (u16*)alloc((size_t)2 * TTOK * QKVD * 2);   // 42.0 MB (only 1st half used)
    u16* qrot    = (u16*)alloc((size_t)TTOK * QD * 2);         // 16.8 MB
    u16* krot    = (u16*)alloc((size_t)NKV * TTOK * HD * 2);   // 2.1 MB
    u16* vrot    = (u16*)alloc((size_t)NKV * TTOK * HD * 2);   // 2.1 MB
    // aliases (dead-after analysis):
    u16* attn = wqkv_bf;               // wqkv_bf dead after gemm1; attn [2048][4096] = 16.8 MB
    u16* p2   = p1;                    // p1 dead after rope; p2 = 2 x [2048][2944] = 24.1 MB

    prep_kernel<<<PREP_QKV_BLOCKS + PREP_RMS_BLOCKS, 256, 0, stream>>>(
        w_qkv, wqkv_bf, x, nscale, h);
    // GEMM1: full-K (z=0 only), 20x8 = 160 gemm blocks + 160 z=1 filler blocks
    // doing the w_out cvt on otherwise-idle CUs
    gemm_bt_8ph<<<dim3(QKVD / 256, TTOK / 256, 2), 512, 163840, stream>>>(
        h, wqkv_bf, p1, QKVD, HIDDEN, HIDDEN, QKVD - 1, QKVD, 1, w_out, wout_bf);
    rope_kernel<<<TTOK, 256, 0, stream>>>(p1, b_qkv, qrot, krot, vrot);
    attn_kernel<<<dim3(TTOK / 16, NKV, 2), 256, 0, stream>>>(qrot, krot, vrot, sinks, attn);
    // GEMM2: split-K z=2 (both z-slices are gemm; no filler), 12x8x2 = 192 blocks
    gemm_bt_8ph<<<dim3((NPAD + 255) / 256, TTOK / 256, 2), 512, 163840, stream>>>(
        attn, wout_bf, p2, NPAD, QD, QD / 2, NPAD - 1, NPAD, 2, nullptr, nullptr);
    reduce2_kernel<<<dim3(3, TTOK), 256, 0, stream>>>(
        p2, p2 + (size_t)TTOK * NPAD, x, b_out, out);
}